// Round 15
// baseline (595.133 us; speedup 1.0000x reference)
//
#include <hip/hip_runtime.h>
#include <hip/hip_bf16.h>

typedef __attribute__((ext_vector_type(8))) short bf16x8;
typedef __attribute__((ext_vector_type(4))) float f32x4;
typedef __attribute__((ext_vector_type(16))) float f32x16;
typedef __attribute__((ext_vector_type(4))) unsigned uint4v;

#define MFMA16(a, b, c) __builtin_amdgcn_mfma_f32_16x16x32_bf16(a, b, c, 0, 0, 0)
#define MFMA32(a, b, c) __builtin_amdgcn_mfma_f32_32x32x16_bf16(a, b, c, 0, 0, 0)

__device__ __forceinline__ unsigned short f2bfn(float f) {
#if defined(__gfx950__)
  __bf16 h = (__bf16)f;
  return __builtin_bit_cast(unsigned short, h);
#else
  union { float f; unsigned u; } x; x.f = f;
  unsigned r = x.u + 0x7fffu + ((x.u >> 16) & 1u);
  return (unsigned short)(r >> 16);
#endif
}

__device__ __forceinline__ unsigned cvtpk(float lo, float hi) {
  unsigned w;
  asm("v_cvt_pk_bf16_f32 %0, %1, %2" : "=v"(w) : "v"(lo), "v"(hi));
  return w;
}

// ---------------- fp32 -> bf16 conversion ----------------
__device__ __forceinline__ void cvt_range(const float* __restrict__ s,
                                          unsigned short* __restrict__ d,
                                          int i, int st, int n8) {
  for (; i < n8; i += st) {
    const float4* sp = reinterpret_cast<const float4*>(s) + 2 * (size_t)i;
    float4 a = sp[0], b = sp[1];
    uint4v o;
    o[0] = cvtpk(a.x, a.y); o[1] = cvtpk(a.z, a.w);
    o[2] = cvtpk(b.x, b.y); o[3] = cvtpk(b.z, b.w);
    reinterpret_cast<uint4v*>(d)[i] = o;
  }
}

__global__ void cvt1_kernel(const float* __restrict__ s, unsigned short* __restrict__ d, int n8) {
  cvt_range(s, d, blockIdx.x * blockDim.x + threadIdx.x, gridDim.x * blockDim.x, n8);
}

// y<4: weight matrices; y==4: Q input (larger, grid-strided). Also zeroes the
// attn->gemmO completion counters (64 ints) when cnt != nullptr.
__global__ void cvt_first_kernel(const float* s0, const float* s1, const float* s2,
                                 const float* s3, unsigned short* d0, unsigned short* d1,
                                 unsigned short* d2, unsigned short* d3, int wn8,
                                 const float* sq, unsigned short* dq, int qn8,
                                 unsigned* cnt) {
  if (cnt && blockIdx.x == 0 && blockIdx.y == 0 && threadIdx.x < 64)
    cnt[threadIdx.x] = 0;
  const float* s; unsigned short* d; int n8;
  switch (blockIdx.y) {
    case 0: s = s0; d = d0; n8 = wn8; break;
    case 1: s = s1; d = d1; n8 = wn8; break;
    case 2: s = s2; d = d2; n8 = wn8; break;
    case 3: s = s3; d = d3; n8 = wn8; break;
    default: s = sq; d = dq; n8 = qn8; break;
  }
  cvt_range(s, d, blockIdx.x * blockDim.x + threadIdx.x, gridDim.x * blockDim.x, n8);
}

// ---------------- GEMM (proven BK=64 config) ----------------
// 1D grid: n = sx & (2^nshift-1), m = sx >> nshift; nshift==3 gets the
// XCD-chunk swizzle (L2 working set 4MB/XCD). Blocks bx >= ngemm piggyback cvt.
// MODE 0: bias[col], out bf16 scattered [B,H,S,64], *oscale
// MODE 1: bias[col], out fp32 row-major [M,N]
// MODE 2: bias[row], out bf16 V^T [BH,64,S]
template <int MODE>
__global__ __launch_bounds__(256) void gemm_kernel(
    const unsigned short* __restrict__ Av, const unsigned short* __restrict__ Bv,
    const float* __restrict__ bias, void* __restrict__ outv,
    int M, int N, int K, float oscale, int nshift, int ngemm,
    const float* __restrict__ csrc, unsigned short* __restrict__ cdst, int cn8) {
  constexpr int BM = 128, BN = 128, BK = 64;
  __shared__ __align__(16) unsigned short As[2][BM * BK];
  __shared__ __align__(16) unsigned short Bs[2][BN * BK];
  const int bx = blockIdx.x;
  const int tid = threadIdx.x;
  if (bx >= ngemm) {
    cvt_range(csrc, cdst, (bx - ngemm) * blockDim.x + tid,
              (gridDim.x - ngemm) * blockDim.x, cn8);
    return;
  }
  int sx = bx;
  if (nshift == 3) sx = (bx & 7) * (ngemm >> 3) + (bx >> 3);
  const int lane = tid & 63, wave = tid >> 6;
  const int wr = wave >> 1, wc = wave & 1;
  const int m0 = (sx >> nshift) * BM, n0 = (sx & ((1 << nshift) - 1)) * BN;
  const int rb = lane & 15, g = lane >> 4;
  const int swz = ((lane & 7) ^ ((lane >> 3) & 7)) * 8;
  f32x4 acc[4][4] = {};

  const unsigned short* Ab = Av + (size_t)m0 * K;
  const unsigned short* Bb = Bv + (size_t)n0 * K;

  auto stage = [&](int buf, int k0) {
#pragma unroll
    for (int i = 0; i < 4; ++i) {
      const int c = wave * 256 + i * 64 + lane;
      const int r = c >> 3;
      __builtin_amdgcn_global_load_lds(
          (const __attribute__((address_space(1))) unsigned int*)(Ab + (size_t)r * K + k0 + swz),
          (__attribute__((address_space(3))) unsigned int*)&As[buf][c * 8], 16, 0, 0);
      __builtin_amdgcn_global_load_lds(
          (const __attribute__((address_space(1))) unsigned int*)(Bb + (size_t)r * K + k0 + swz),
          (__attribute__((address_space(3))) unsigned int*)&Bs[buf][c * 8], 16, 0, 0);
    }
  };

  const int nt = K / BK;
  stage(0, 0);
  int cur = 0;
  for (int t = 0; t < nt; ++t) {
    __syncthreads();
    if (t + 1 < nt) stage(cur ^ 1, (t + 1) * BK);
    const unsigned short* A_ = As[cur];
    const unsigned short* B_ = Bs[cur];
#pragma unroll
    for (int kc = 0; kc < 2; ++kc) {
      bf16x8 af[4], bfr[4];
#pragma unroll
      for (int mi = 0; mi < 4; ++mi)
        af[mi] = *reinterpret_cast<const bf16x8*>(
            &A_[(wr * 64 + mi * 16 + rb) * 64 + (((kc * 4 + g) ^ (rb & 7)) * 8)]);
#pragma unroll
      for (int ni = 0; ni < 4; ++ni)
        bfr[ni] = *reinterpret_cast<const bf16x8*>(
            &B_[(wc * 64 + ni * 16 + rb) * 64 + (((kc * 4 + g) ^ (rb & 7)) * 8)]);
#pragma unroll
      for (int mi = 0; mi < 4; ++mi)
#pragma unroll
        for (int ni = 0; ni < 4; ++ni)
          acc[mi][ni] = MFMA16(af[mi], bfr[ni], acc[mi][ni]);
    }
    cur ^= 1;
  }

#pragma unroll
  for (int mi = 0; mi < 4; ++mi) {
#pragma unroll
    for (int ni = 0; ni < 4; ++ni) {
      int col = n0 + wc * 64 + ni * 16 + rb;
      if constexpr (MODE != 2) {
        float bvv = bias[col];
#pragma unroll
        for (int j = 0; j < 4; ++j) {
          int row = m0 + wr * 64 + mi * 16 + g * 4 + j;
          float v = acc[mi][ni][j] + bvv;
          if constexpr (MODE == 0) {
            v *= oscale;
            int b = row >> 11, s = row & 2047;
            int h = col >> 6, e = col & 63;
            ((unsigned short*)outv)[((size_t)(b * 16 + h) * 2048 + s) * 64 + e] = f2bfn(v);
          } else {
            ((float*)outv)[(size_t)row * N + col] = v;
          }
        }
      } else {
        int bb = col >> 11, s = col & 2047;
#pragma unroll
        for (int j = 0; j < 4; ++j) {
          int row = m0 + wr * 64 + mi * 16 + g * 4 + j;
          float v = acc[mi][ni][j] + bias[row];
          int h = row >> 6, e = row & 63;
          ((unsigned short*)outv)[((size_t)(bb * 16 + h) * 64 + e) * 2048 + s] = f2bfn(v);
        }
      }
    }
  }
}

// ---------------- merged attention + output projection ----------------
// bx < 1024: attn block (round-12 proven attn7 body); signals cnt[b*16+qti]
//            (device-scope release) after writing its ctx rows.
// bx >= 1024: gemmO block (BK=32 body, 32KB LDS union with attn); spins until
//            its (b,qti) ctx panel is complete (16 h-blocks), then computes
//            out[m0..m0+127][n0..n0+127] fp32. Panel order matches attn
//            completion order (qti descending); each XCD keeps one B n-tile hot.
__global__ __launch_bounds__(256, 4) void attn_gemmo_kernel(
    const unsigned short* __restrict__ Qp, const unsigned short* __restrict__ Kp,
    const unsigned short* __restrict__ Vtp, unsigned short* __restrict__ ctx,
    const unsigned short* __restrict__ Wo, const float* __restrict__ bo,
    float* __restrict__ out, unsigned* __restrict__ cnt) {
  constexpr int S = 2048;
  __shared__ __align__(16) unsigned short smem[16384];  // 32 KB union
  const int bx = blockIdx.x;
  const int tid = threadIdx.x;
  const int lane = tid & 63, wave = tid >> 6;

  if (bx < 1024) {
    // ================= attention =================
    unsigned short (*Ks)[4096] = reinterpret_cast<unsigned short(*)[4096]>(smem);
    unsigned short (*Vs)[4096] = reinterpret_cast<unsigned short(*)[4096]>(smem + 8192);
    const int bh = bx & 63;
    const int qti = 15 - (bx >> 6);  // heavy tiles first
    const int l31 = lane & 31, hb = lane >> 5;
    const int x7 = l31 & 7;
    const int qw = qti * 128 + wave * 32;
    const unsigned short* Qb = Qp + (size_t)bh * S * 64;
    const unsigned short* Kb = Kp + (size_t)bh * S * 64;
    const unsigned short* Vb = Vtp + (size_t)bh * 64 * S;

    bf16x8 qg[4];
#pragma unroll
    for (int kc = 0; kc < 4; ++kc)
      qg[kc] = *reinterpret_cast<const bf16x8*>(
          Qb + (size_t)(qw + l31) * 64 + 16 * kc + 8 * hb);

    bf16x8 ones;
#pragma unroll
    for (int i = 0; i < 8; ++i) ones[i] = (short)0x3F80;

    f32x16 ls = {};
    f32x16 o[2] = {};
    const int sswz = ((lane & 7) ^ (lane >> 3)) * 8;
    const int nt = qti * 2 + 2;

    const int ci0 = wave * 2 * 64 + lane, ci1 = ci0 + 64;
    const int r0 = wave * 16 + (lane >> 3), r1 = r0 + 8;
    const int rs0 = (r0 & 51) | ((r0 & 4) << 1) | ((r0 & 8) >> 1);
    const int rs1 = (r1 & 51) | ((r1 & 4) << 1) | ((r1 & 8) >> 1);
    const unsigned short* ks0 = Kb + (size_t)rs0 * 64 + sswz;
    const unsigned short* ks1 = Kb + (size_t)rs1 * 64 + sswz;
    const unsigned short* vs0 = Vb + (size_t)r0 * S + sswz;
    const unsigned short* vs1 = Vb + (size_t)r1 * S + sswz;

    auto stage = [&](int buf) {
      __builtin_amdgcn_global_load_lds(
          (const __attribute__((address_space(1))) unsigned int*)ks0,
          (__attribute__((address_space(3))) unsigned int*)&Ks[buf][ci0 * 8], 16, 0, 0);
      __builtin_amdgcn_global_load_lds(
          (const __attribute__((address_space(1))) unsigned int*)ks1,
          (__attribute__((address_space(3))) unsigned int*)&Ks[buf][ci1 * 8], 16, 0, 0);
      __builtin_amdgcn_global_load_lds(
          (const __attribute__((address_space(1))) unsigned int*)vs0,
          (__attribute__((address_space(3))) unsigned int*)&Vs[buf][ci0 * 8], 16, 0, 0);
      __builtin_amdgcn_global_load_lds(
          (const __attribute__((address_space(1))) unsigned int*)vs1,
          (__attribute__((address_space(3))) unsigned int*)&Vs[buf][ci1 * 8], 16, 0, 0);
      ks0 += 4096; ks1 += 4096;
      vs0 += 64; vs1 += 64;
    };

    stage(0);

    for (int it = 0; it < nt; ++it) {
      __syncthreads();
      if (it + 1 < nt) stage((it + 1) & 1);
      const int kv0 = 64 * it;
      if (kv0 <= qw + 31) {
        const unsigned short* K_ = Ks[it & 1];
        const unsigned short* V_ = Vs[it & 1];
        f32x16 sacc[2] = {};
        __builtin_amdgcn_s_setprio(1);
#pragma unroll
        for (int kc = 0; kc < 4; ++kc) {
          bf16x8 kf0 = *reinterpret_cast<const bf16x8*>(
              &K_[l31 * 64 + ((2 * kc + hb) ^ x7) * 8]);
          bf16x8 kf1 = *reinterpret_cast<const bf16x8*>(
              &K_[(32 + l31) * 64 + ((2 * kc + hb) ^ x7) * 8]);
          sacc[0] = MFMA32(kf0, qg[kc], sacc[0]);
          sacc[1] = MFMA32(kf1, qg[kc], sacc[1]);
        }
        __builtin_amdgcn_s_setprio(0);
        if (kv0 + 63 > qw) {
          const int qrel = qw + l31 - kv0 - 8 * hb;
#pragma unroll
          for (int mi = 0; mi < 2; ++mi)
#pragma unroll
            for (int r = 0; r < 16; ++r) {
              int koff = (r & 7) + 16 * (r >> 3) + 32 * mi;
              if (koff > qrel) sacc[mi][r] = -1e30f;
            }
        }
        float p0[16], p1[16];
#pragma unroll
        for (int r = 0; r < 16; ++r) p0[r] = __builtin_amdgcn_exp2f(sacc[0][r]);
#pragma unroll
        for (int r = 0; r < 16; ++r) p1[r] = __builtin_amdgcn_exp2f(sacc[1][r]);
        unsigned pw[2][8];
#pragma unroll
        for (int i = 0; i < 8; ++i) pw[0][i] = cvtpk(p0[2 * i], p0[2 * i + 1]);
#pragma unroll
        for (int i = 0; i < 8; ++i) pw[1][i] = cvtpk(p1[2 * i], p1[2 * i + 1]);
        __builtin_amdgcn_s_setprio(1);
#pragma unroll
        for (int c = 0; c < 4; ++c) {
          union { unsigned u[4]; bf16x8 v; } pu;
          pu.u[0] = pw[c >> 1][(c & 1) * 4 + 0];
          pu.u[1] = pw[c >> 1][(c & 1) * 4 + 1];
          pu.u[2] = pw[c >> 1][(c & 1) * 4 + 2];
          pu.u[3] = pw[c >> 1][(c & 1) * 4 + 3];
#pragma unroll
          for (int db = 0; db < 2; ++db) {
            bf16x8 vf = *reinterpret_cast<const bf16x8*>(
                &V_[(32 * db + l31) * 64 + ((2 * c + hb) ^ x7) * 8]);
            o[db] = MFMA32(vf, pu.v, o[db]);
          }
          ls = MFMA32(ones, pu.v, ls);
        }
        __builtin_amdgcn_s_setprio(0);
      }
    }

    const float inv = 1.0f / ls[0];
    const int b = bh >> 4, h = bh & 15;
    const int q = qw + l31;
    unsigned short* cp = ctx + ((size_t)(b * 2048 + q) * 1024) + h * 64;
#pragma unroll
    for (int db = 0; db < 2; ++db)
#pragma unroll
      for (int i = 0; i < 8; ++i) {
        unsigned w = cvtpk(o[db][2 * i] * inv, o[db][2 * i + 1] * inv);
        int d = 32 * db + ((2 * i) & 3) + 8 * (i >> 1) + 4 * hb;
        *reinterpret_cast<unsigned*>(cp + d) = w;
      }

    // publish: ctx rows for (b, qti, h) are written
    __threadfence();
    __syncthreads();
    if (tid == 0)
      __hip_atomic_fetch_add(&cnt[b * 16 + qti], 1u, __ATOMIC_RELEASE,
                             __HIP_MEMORY_SCOPE_AGENT);
  } else {
    // ================= output projection (BK=32, waits on ctx panel) =================
    unsigned short (*As)[4096] = reinterpret_cast<unsigned short(*)[4096]>(smem);
    unsigned short (*Bs)[4096] = reinterpret_cast<unsigned short(*)[4096]>(smem + 8192);
    const int ox = bx - 1024;          // 0..511
    const int p = ox >> 3;             // 64 panels, qti-descending
    const int qd = p >> 2, bb = p & 3, qti = 15 - qd;
    const int m0 = bb * 2048 + qti * 128;
    const int n0 = (ox & 7) * 128;
    constexpr int K = 1024;

    if (tid == 0) {
      while (__hip_atomic_load(&cnt[bb * 16 + qti], __ATOMIC_ACQUIRE,
                               __HIP_MEMORY_SCOPE_AGENT) < 16u)
        __builtin_amdgcn_s_sleep(16);
    }
    __syncthreads();
    __threadfence();

    const int wr = wave >> 1, wc = wave & 1;
    const int rb = lane & 15, g = lane >> 4;
    const int swz = ((lane & 3) ^ ((lane >> 3) & 3)) * 8;
    const int rk = (rb >> 1) & 3;
    f32x4 acc[4][4] = {};
    const unsigned short* Ab = ctx + (size_t)m0 * K;
    const unsigned short* Bb = Wo + (size_t)n0 * K;

    auto stageO = [&](int buf, int k0) {
#pragma unroll
      for (int i = 0; i < 2; ++i) {
        const int c = wave * 128 + i * 64 + lane;
        const int r = c >> 2;
        __builtin_amdgcn_global_load_lds(
            (const __attribute__((address_space(1))) unsigned int*)(Ab + (size_t)r * K + k0 + swz),
            (__attribute__((address_space(3))) unsigned int*)&As[buf][c * 8], 16, 0, 0);
        __builtin_amdgcn_global_load_lds(
            (const __attribute__((address_space(1))) unsigned int*)(Bb + (size_t)r * K + k0 + swz),
            (__attribute__((address_space(3))) unsigned int*)&Bs[buf][c * 8], 16, 0, 0);
      }
    };

    stageO(0, 0);
    int cur = 0;
    for (int t = 0; t < K / 32; ++t) {
      __syncthreads();
      if (t + 1 < K / 32) stageO(cur ^ 1, (t + 1) * 32);
      const unsigned short* A_ = As[cur];
      const unsigned short* B_ = Bs[cur];
      bf16x8 af[4], bfr[4];
#pragma unroll
      for (int mi = 0; mi < 4; ++mi)
        af[mi] = *reinterpret_cast<const bf16x8*>(
            &A_[(wr * 64 + mi * 16 + rb) * 32 + ((g ^ rk) * 8)]);
#pragma unroll
      for (int ni = 0; ni < 4; ++ni)
        bfr[ni] = *reinterpret_cast<const bf16x8*>(
            &B_[(wc * 64 + ni * 16 + rb) * 32 + ((g ^ rk) * 8)]);
#pragma unroll
      for (int mi = 0; mi < 4; ++mi)
#pragma unroll
        for (int ni = 0; ni < 4; ++ni)
          acc[mi][ni] = MFMA16(af[mi], bfr[ni], acc[mi][ni]);
      cur ^= 1;
    }

#pragma unroll
    for (int mi = 0; mi < 4; ++mi)
#pragma unroll
      for (int ni = 0; ni < 4; ++ni) {
        int col = n0 + wc * 64 + ni * 16 + rb;
        float bvv = bo[col];
#pragma unroll
        for (int j = 0; j < 4; ++j) {
          int row = m0 + wr * 64 + mi * 16 + g * 4 + j;
          out[(size_t)row * 1024 + col] = acc[mi][ni][j] + bvv;
        }
      }
  }
}

// ---------------- standalone attention (serial fallback) ----------------
__global__ __launch_bounds__(256) void attn7_kernel(
    const unsigned short* __restrict__ Qp, const unsigned short* __restrict__ Kp,
    const unsigned short* __restrict__ Vtp, unsigned short* __restrict__ ctx) {
  constexpr int S = 2048;
  __shared__ __align__(16) unsigned short Ks[2][64 * 64];
  __shared__ __align__(16) unsigned short Vs[2][64 * 64];
  const int bx = blockIdx.x;
  const int bh = bx & 63;
  const int qti = 15 - (bx >> 6);
  const int tid = threadIdx.x, wave = tid >> 6, lane = tid & 63;
  const int l31 = lane & 31, hb = lane >> 5;
  const int x7 = l31 & 7;
  const int qw = qti * 128 + wave * 32;
  const unsigned short* Qb = Qp + (size_t)bh * S * 64;
  const unsigned short* Kb = Kp + (size_t)bh * S * 64;
  const unsigned short* Vb = Vtp + (size_t)bh * 64 * S;

  bf16x8 qg[4];
#pragma unroll
  for (int kc = 0; kc < 4; ++kc)
    qg[kc] = *reinterpret_cast<const bf16x8*>(
        Qb + (size_t)(qw + l31) * 64 + 16 * kc + 8 * hb);

  bf16x8 ones;
#pragma unroll
  for (int i = 0; i < 8; ++i) ones[i] = (short)0x3F80;

  f32x16 ls = {};
  f32x16 o[2] = {};
  const int sswz = ((lane & 7) ^ (lane >> 3)) * 8;
  const int nt = qti * 2 + 2;

  const int ci0 = wave * 2 * 64 + lane, ci1 = ci0 + 64;
  const int r0 = wave * 16 + (lane >> 3), r1 = r0 + 8;
  const int rs0 = (r0 & 51) | ((r0 & 4) << 1) | ((r0 & 8) >> 1);
  const int rs1 = (r1 & 51) | ((r1 & 4) << 1) | ((r1 & 8) >> 1);
  const unsigned short* ks0 = Kb + (size_t)rs0 * 64 + sswz;
  const unsigned short* ks1 = Kb + (size_t)rs1 * 64 + sswz;
  const unsigned short* vs0 = Vb + (size_t)r0 * S + sswz;
  const unsigned short* vs1 = Vb + (size_t)r1 * S + sswz;

  auto stage = [&](int buf) {
    __builtin_amdgcn_global_load_lds(
        (const __attribute__((address_space(1))) unsigned int*)ks0,
        (__attribute__((address_space(3))) unsigned int*)&Ks[buf][ci0 * 8], 16, 0, 0);
    __builtin_amdgcn_global_load_lds(
        (const __attribute__((address_space(1))) unsigned int*)ks1,
        (__attribute__((address_space(3))) unsigned int*)&Ks[buf][ci1 * 8], 16, 0, 0);
    __builtin_amdgcn_global_load_lds(
        (const __attribute__((address_space(1))) unsigned int*)vs0,
        (__attribute__((address_space(3))) unsigned int*)&Vs[buf][ci0 * 8], 16, 0, 0);
    __builtin_amdgcn_global_load_lds(
        (const __attribute__((address_space(1))) unsigned int*)vs1,
        (__attribute__((address_space(3))) unsigned int*)&Vs[buf][ci1 * 8], 16, 0, 0);
    ks0 += 4096; ks1 += 4096;
    vs0 += 64; vs1 += 64;
  };

  stage(0);

  for (int it = 0; it < nt; ++it) {
    __syncthreads();
    if (it + 1 < nt) stage((it + 1) & 1);
    const int kv0 = 64 * it;
    if (kv0 <= qw + 31) {
      const unsigned short* K_ = Ks[it & 1];
      const unsigned short* V_ = Vs[it & 1];
      f32x16 sacc[2] = {};
      __builtin_amdgcn_s_setprio(1);
#pragma unroll
      for (int kc = 0; kc < 4; ++kc) {
        bf16x8 kf0 = *reinterpret_cast<const bf16x8*>(
            &K_[l31 * 64 + ((2 * kc + hb) ^ x7) * 8]);
        bf16x8 kf1 = *reinterpret_cast<const bf16x8*>(
            &K_[(32 + l31) * 64 + ((2 * kc + hb) ^ x7) * 8]);
        sacc[0] = MFMA32(kf0, qg[kc], sacc[0]);
        sacc[1] = MFMA32(kf1, qg[kc], sacc[1]);
      }
      __builtin_amdgcn_s_setprio(0);
      if (kv0 + 63 > qw) {
        const int qrel = qw + l31 - kv0 - 8 * hb;
#pragma unroll
        for (int mi = 0; mi < 2; ++mi)
#pragma unroll
          for (int r = 0; r < 16; ++r) {
            int koff = (r & 7) + 16 * (r >> 3) + 32 * mi;
            if (koff > qrel) sacc[mi][r] = -1e30f;
          }
      }
      float p0[16], p1[16];
#pragma unroll
      for (int r = 0; r < 16; ++r) p0[r] = __builtin_amdgcn_exp2f(sacc[0][r]);
#pragma unroll
      for (int r = 0; r < 16; ++r) p1[r] = __builtin_amdgcn_exp2f(sacc[1][r]);
      unsigned pw[2][8];
#pragma unroll
      for (int i = 0; i < 8; ++i) pw[0][i] = cvtpk(p0[2 * i], p0[2 * i + 1]);
#pragma unroll
      for (int i = 0; i < 8; ++i) pw[1][i] = cvtpk(p1[2 * i], p1[2 * i + 1]);
      __builtin_amdgcn_s_setprio(1);
#pragma unroll
      for (int c = 0; c < 4; ++c) {
        union { unsigned u[4]; bf16x8 v; } pu;
        pu.u[0] = pw[c >> 1][(c & 1) * 4 + 0];
        pu.u[1] = pw[c >> 1][(c & 1) * 4 + 1];
        pu.u[2] = pw[c >> 1][(c & 1) * 4 + 2];
        pu.u[3] = pw[c >> 1][(c & 1) * 4 + 3];
#pragma unroll
        for (int db = 0; db < 2; ++db) {
          bf16x8 vf = *reinterpret_cast<const bf16x8*>(
              &V_[(32 * db + l31) * 64 + ((2 * c + hb) ^ x7) * 8]);
          o[db] = MFMA32(vf, pu.v, o[db]);
        }
        ls = MFMA32(ones, pu.v, ls);
      }
      __builtin_amdgcn_s_setprio(0);
    }
  }

  const float inv = 1.0f / ls[0];
  const int b = bh >> 4, h = bh & 15;
  const int q = qw + l31;
  unsigned short* cp = ctx + ((size_t)(b * 2048 + q) * 1024) + h * 64;
#pragma unroll
  for (int db = 0; db < 2; ++db)
#pragma unroll
    for (int i = 0; i < 8; ++i) {
      unsigned w = cvtpk(o[db][2 * i] * inv, o[db][2 * i + 1] * inv);
      int d = 32 * db + ((2 * i) & 3) + 8 * (i >> 1) + 4 * hb;
      *reinterpret_cast<unsigned*>(cp + d) = w;
    }
}

extern "C" void kernel_launch(void* const* d_in, const int* in_sizes, int n_in,
                              void* d_out, int out_size, void* d_ws, size_t ws_size,
                              hipStream_t stream) {
  const float* in_q = (const float*)d_in[0];
  const float* in_k = (const float*)d_in[1];
  const float* in_v = (const float*)d_in[2];
  const float* WQw = (const float*)d_in[3];
  const float* WQb = (const float*)d_in[4];
  const float* WKw = (const float*)d_in[5];
  const float* WKb = (const float*)d_in[6];
  const float* WVw = (const float*)d_in[7];
  const float* WVb = (const float*)d_in[8];
  const float* Ww  = (const float*)d_in[9];
  const float* Wb  = (const float*)d_in[10];
  float* out = (float*)d_out;

  constexpr size_t PROJ = (size_t)4 * 16 * 2048 * 64;  // 8,388,608 elems
  constexpr size_t WSZ = (size_t)1024 * 1024;
  const float qscale = 0.03125f * 1.4426950408889634f;  // 1/sqrt(1024) * log2(e)
  unsigned short* wsp = (unsigned short*)d_ws;

  const bool fused = ws_size >= (6 * PROJ + 4 * WSZ) * sizeof(unsigned short) + 256;

  if (fused) {
    unsigned short* Qp   = wsp;
    unsigned short* Kp   = wsp + PROJ;
    unsigned short* Vt   = wsp + 2 * PROJ;
    unsigned short* inq  = wsp + 3 * PROJ;  // later aliased as ctx
    unsigned short* ctx  = inq;
    unsigned short* ink  = wsp + 4 * PROJ;
    unsigned short* inv  = wsp + 5 * PROJ;
    unsigned short* wq16 = wsp + 6 * PROJ;
    unsigned short* wk16 = wq16 + WSZ;
    unsigned short* wv16 = wk16 + WSZ;
    unsigned short* ww16 = wv16 + WSZ;
    unsigned* cnt = (unsigned*)(ww16 + WSZ);

    cvt_first_kernel<<<dim3(1024, 5), 256, 0, stream>>>(
        WQw, WKw, WVw, Ww, wq16, wk16, wv16, ww16, (int)(WSZ / 8),
        in_q, inq, (int)(PROJ / 8), cnt);
    gemm_kernel<0><<<2560, 256, 0, stream>>>(inq, wq16, WQb, Qp, 8192, 1024, 1024,
                                             qscale, 3, 512, in_k, ink, (int)(PROJ / 8));
    gemm_kernel<0><<<2560, 256, 0, stream>>>(ink, wk16, WKb, Kp, 8192, 1024, 1024,
                                             1.0f, 3, 512, in_v, inv, (int)(PROJ / 8));
    gemm_kernel<2><<<512, 256, 0, stream>>>(wv16, inv, WVb, Vt, 1024, 8192, 1024,
                                            1.0f, 6, 512, nullptr, nullptr, 0);
    // merged attention + output projection (overlapped via counters)
    attn_gemmo_kernel<<<1536, 256, 0, stream>>>(Qp, Kp, Vt, ctx, ww16, Wb, out, cnt);
  } else {
    unsigned short* Qp   = wsp;
    unsigned short* Kp   = wsp + PROJ;
    unsigned short* Vt   = wsp + 2 * PROJ;
    unsigned short* in16 = wsp + 3 * PROJ;
    unsigned short* ctx  = in16;
    unsigned short* wq16 = wsp + 4 * PROJ;
    unsigned short* wk16 = wq16 + WSZ;
    unsigned short* wv16 = wk16 + WSZ;
    unsigned short* ww16 = wv16 + WSZ;

    cvt_first_kernel<<<dim3(1024, 5), 256, 0, stream>>>(
        WQw, WKw, WVw, Ww, wq16, wk16, wv16, ww16, (int)(WSZ / 8),
        in_q, in16, (int)(PROJ / 8), nullptr);
    gemm_kernel<0><<<512, 256, 0, stream>>>(in16, wq16, WQb, Qp, 8192, 1024, 1024,
                                            qscale, 3, 512, nullptr, nullptr, 0);
    cvt1_kernel<<<2048, 256, 0, stream>>>(in_k, in16, (int)(PROJ / 8));
    gemm_kernel<0><<<512, 256, 0, stream>>>(in16, wk16, WKb, Kp, 8192, 1024, 1024,
                                            1.0f, 3, 512, nullptr, nullptr, 0);
    cvt1_kernel<<<2048, 256, 0, stream>>>(in_v, in16, (int)(PROJ / 8));
    gemm_kernel<2><<<512, 256, 0, stream>>>(wv16, in16, WVb, Vt, 1024, 8192, 1024,
                                            1.0f, 6, 512, nullptr, nullptr, 0);
    attn7_kernel<<<1024, 256, 0, stream>>>(Qp, Kp, Vt, ctx);
    gemm_kernel<1><<<512, 256, 0, stream>>>(ctx, ww16, Wb, out, 8192, 1024, 1024,
                                            1.0f, 3, 512, nullptr, nullptr, 0);
  }
}

// Round 16
// 214.531 us; speedup vs baseline: 2.7741x; 2.7741x over previous
//
#include <hip/hip_runtime.h>
#include <hip/hip_bf16.h>

typedef __attribute__((ext_vector_type(8))) short bf16x8;
typedef __attribute__((ext_vector_type(4))) float f32x4;
typedef __attribute__((ext_vector_type(16))) float f32x16;
typedef __attribute__((ext_vector_type(4))) unsigned uint4v;

#define MFMA16(a, b, c) __builtin_amdgcn_mfma_f32_16x16x32_bf16(a, b, c, 0, 0, 0)
#define MFMA32(a, b, c) __builtin_amdgcn_mfma_f32_32x32x16_bf16(a, b, c, 0, 0, 0)

__device__ __forceinline__ unsigned short f2bfn(float f) {
#if defined(__gfx950__)
  __bf16 h = (__bf16)f;
  return __builtin_bit_cast(unsigned short, h);
#else
  union { float f; unsigned u; } x; x.f = f;
  unsigned r = x.u + 0x7fffu + ((x.u >> 16) & 1u);
  return (unsigned short)(r >> 16);
#endif
}

__device__ __forceinline__ unsigned cvtpk(float lo, float hi) {
  unsigned w;
  asm("v_cvt_pk_bf16_f32 %0, %1, %2" : "=v"(w) : "v"(lo), "v"(hi));
  return w;
}

// ---------------- fp32 -> bf16 conversion ----------------
__device__ __forceinline__ void cvt_range(const float* __restrict__ s,
                                          unsigned short* __restrict__ d,
                                          int i, int st, int n8) {
  for (; i < n8; i += st) {
    const float4* sp = reinterpret_cast<const float4*>(s) + 2 * (size_t)i;
    float4 a = sp[0], b = sp[1];
    uint4v o;
    o[0] = cvtpk(a.x, a.y); o[1] = cvtpk(a.z, a.w);
    o[2] = cvtpk(b.x, b.y); o[3] = cvtpk(b.z, b.w);
    reinterpret_cast<uint4v*>(d)[i] = o;
  }
}

__global__ void cvt1_kernel(const float* __restrict__ s, unsigned short* __restrict__ d, int n8) {
  cvt_range(s, d, blockIdx.x * blockDim.x + threadIdx.x, gridDim.x * blockDim.x, n8);
}

// y<4: weight matrices; y==4: Q input (larger, grid-strided)
__global__ void cvt_first_kernel(const float* s0, const float* s1, const float* s2,
                                 const float* s3, unsigned short* d0, unsigned short* d1,
                                 unsigned short* d2, unsigned short* d3, int wn8,
                                 const float* sq, unsigned short* dq, int qn8) {
  const float* s; unsigned short* d; int n8;
  switch (blockIdx.y) {
    case 0: s = s0; d = d0; n8 = wn8; break;
    case 1: s = s1; d = d1; n8 = wn8; break;
    case 2: s = s2; d = d2; n8 = wn8; break;
    case 3: s = s3; d = d3; n8 = wn8; break;
    default: s = sq; d = dq; n8 = qn8; break;
  }
  cvt_range(s, d, blockIdx.x * blockDim.x + threadIdx.x, gridDim.x * blockDim.x, n8);
}

// ---------------- GEMM (proven BK=64 config, round-14) ----------------
// 1D grid: n = sx & (2^nshift-1), m = sx >> nshift; nshift==3 gets the
// XCD-chunk swizzle (4MB working set per XCD). Blocks bx >= ngemm piggyback cvt.
// MODE 0: bias[col], out bf16 scattered [B,H,S,64], *oscale
// MODE 1: bias[col], out fp32 row-major [M,N]
// MODE 2: bias[row], out bf16 V^T [BH,64,S]
template <int MODE>
__global__ __launch_bounds__(256) void gemm_kernel(
    const unsigned short* __restrict__ Av, const unsigned short* __restrict__ Bv,
    const float* __restrict__ bias, void* __restrict__ outv,
    int M, int N, int K, float oscale, int nshift, int ngemm,
    const float* __restrict__ csrc, unsigned short* __restrict__ cdst, int cn8) {
  constexpr int BM = 128, BN = 128, BK = 64;
  __shared__ __align__(16) unsigned short As[2][BM * BK];
  __shared__ __align__(16) unsigned short Bs[2][BN * BK];
  const int bx = blockIdx.x;
  const int tid = threadIdx.x;
  if (bx >= ngemm) {
    cvt_range(csrc, cdst, (bx - ngemm) * blockDim.x + tid,
              (gridDim.x - ngemm) * blockDim.x, cn8);
    return;
  }
  int sx = bx;
  if (nshift == 3) sx = (bx & 7) * (ngemm >> 3) + (bx >> 3);
  const int lane = tid & 63, wave = tid >> 6;
  const int wr = wave >> 1, wc = wave & 1;
  const int m0 = (sx >> nshift) * BM, n0 = (sx & ((1 << nshift) - 1)) * BN;
  const int rb = lane & 15, g = lane >> 4;
  const int swz = ((lane & 7) ^ ((lane >> 3) & 7)) * 8;
  f32x4 acc[4][4] = {};

  const unsigned short* Ab = Av + (size_t)m0 * K;
  const unsigned short* Bb = Bv + (size_t)n0 * K;

  auto stage = [&](int buf, int k0) {
#pragma unroll
    for (int i = 0; i < 4; ++i) {
      const int c = wave * 256 + i * 64 + lane;
      const int r = c >> 3;
      __builtin_amdgcn_global_load_lds(
          (const __attribute__((address_space(1))) unsigned int*)(Ab + (size_t)r * K + k0 + swz),
          (__attribute__((address_space(3))) unsigned int*)&As[buf][c * 8], 16, 0, 0);
      __builtin_amdgcn_global_load_lds(
          (const __attribute__((address_space(1))) unsigned int*)(Bb + (size_t)r * K + k0 + swz),
          (__attribute__((address_space(3))) unsigned int*)&Bs[buf][c * 8], 16, 0, 0);
    }
  };

  const int nt = K / BK;
  stage(0, 0);
  int cur = 0;
  for (int t = 0; t < nt; ++t) {
    __syncthreads();
    if (t + 1 < nt) stage(cur ^ 1, (t + 1) * BK);
    const unsigned short* A_ = As[cur];
    const unsigned short* B_ = Bs[cur];
#pragma unroll
    for (int kc = 0; kc < 2; ++kc) {
      bf16x8 af[4], bfr[4];
#pragma unroll
      for (int mi = 0; mi < 4; ++mi)
        af[mi] = *reinterpret_cast<const bf16x8*>(
            &A_[(wr * 64 + mi * 16 + rb) * 64 + (((kc * 4 + g) ^ (rb & 7)) * 8)]);
#pragma unroll
      for (int ni = 0; ni < 4; ++ni)
        bfr[ni] = *reinterpret_cast<const bf16x8*>(
            &B_[(wc * 64 + ni * 16 + rb) * 64 + (((kc * 4 + g) ^ (rb & 7)) * 8)]);
#pragma unroll
      for (int mi = 0; mi < 4; ++mi)
#pragma unroll
        for (int ni = 0; ni < 4; ++ni)
          acc[mi][ni] = MFMA16(af[mi], bfr[ni], acc[mi][ni]);
    }
    cur ^= 1;
  }

#pragma unroll
  for (int mi = 0; mi < 4; ++mi) {
#pragma unroll
    for (int ni = 0; ni < 4; ++ni) {
      int col = n0 + wc * 64 + ni * 16 + rb;
      if constexpr (MODE != 2) {
        float bvv = bias[col];
#pragma unroll
        for (int j = 0; j < 4; ++j) {
          int row = m0 + wr * 64 + mi * 16 + g * 4 + j;
          float v = acc[mi][ni][j] + bvv;
          if constexpr (MODE == 0) {
            v *= oscale;
            int b = row >> 11, s = row & 2047;
            int h = col >> 6, e = col & 63;
            ((unsigned short*)outv)[((size_t)(b * 16 + h) * 2048 + s) * 64 + e] = f2bfn(v);
          } else {
            ((float*)outv)[(size_t)row * N + col] = v;
          }
        }
      } else {
        int bb = col >> 11, s = col & 2047;
#pragma unroll
        for (int j = 0; j < 4; ++j) {
          int row = m0 + wr * 64 + mi * 16 + g * 4 + j;
          float v = acc[mi][ni][j] + bias[row];
          int h = row >> 6, e = row & 63;
          ((unsigned short*)outv)[((size_t)(bb * 16 + h) * 64 + e) * 2048 + s] = f2bfn(v);
        }
      }
    }
  }
}

// ---------------- flash attention: dual q-tile per block ----------------
// Each block owns q-tiles {15-pi, pi} (pi = bx>>6, 512 blocks) and processes
// both in ONE shared kv-scan: tile B's kv range is a subset of tile A's, so
// each staged K/V tile feeds both tiles' compute (staging bytes and barriers
// per unit compute halved; per-block compute ~constant 34 iters -> balanced;
// all blocks scan kv from 0 in lockstep -> L2 sharing preserved).
// Body per tile = round-12 proven attn7 (32x32 swapped, no-max softmax,
// MFMA row-sum, swap23 K permutation, zero cross-lane P handoff).
__global__ __launch_bounds__(256) void attn8_kernel(
    const unsigned short* __restrict__ Qp, const unsigned short* __restrict__ Kp,
    const unsigned short* __restrict__ Vtp, unsigned short* __restrict__ ctx) {
  constexpr int S = 2048;
  __shared__ __align__(16) unsigned short Ks[2][64 * 64];
  __shared__ __align__(16) unsigned short Vs[2][64 * 64];
  const int bx = blockIdx.x;
  const int bh = bx & 63;
  const int pi = bx >> 6;            // 0..7
  const int qtiA = 15 - pi;          // heavy tile
  const int qtiB = pi;               // light tile
  const int tid = threadIdx.x, wave = tid >> 6, lane = tid & 63;
  const int l31 = lane & 31, hb = lane >> 5;
  const int x7 = l31 & 7;
  const int qwA = qtiA * 128 + wave * 32;
  const int qwB = qtiB * 128 + wave * 32;
  const unsigned short* Qb = Qp + (size_t)bh * S * 64;
  const unsigned short* Kb = Kp + (size_t)bh * S * 64;
  const unsigned short* Vb = Vtp + (size_t)bh * 64 * S;

  bf16x8 qgA[4], qgB[4];
#pragma unroll
  for (int kc = 0; kc < 4; ++kc) {
    qgA[kc] = *reinterpret_cast<const bf16x8*>(
        Qb + (size_t)(qwA + l31) * 64 + 16 * kc + 8 * hb);
    qgB[kc] = *reinterpret_cast<const bf16x8*>(
        Qb + (size_t)(qwB + l31) * 64 + 16 * kc + 8 * hb);
  }

  bf16x8 ones;
#pragma unroll
  for (int i = 0; i < 8; ++i) ones[i] = (short)0x3F80;

  f32x16 lsA = {}, lsB = {};
  f32x16 oA[2] = {}, oB[2] = {};
  const int sswz = ((lane & 7) ^ (lane >> 3)) * 8;
  const int nt = qtiA * 2 + 2;

  const int ci0 = wave * 2 * 64 + lane, ci1 = ci0 + 64;
  const int r0 = wave * 16 + (lane >> 3), r1 = r0 + 8;
  const int rs0 = (r0 & 51) | ((r0 & 4) << 1) | ((r0 & 8) >> 1);
  const int rs1 = (r1 & 51) | ((r1 & 4) << 1) | ((r1 & 8) >> 1);
  const unsigned short* ks0 = Kb + (size_t)rs0 * 64 + sswz;
  const unsigned short* ks1 = Kb + (size_t)rs1 * 64 + sswz;
  const unsigned short* vs0 = Vb + (size_t)r0 * S + sswz;
  const unsigned short* vs1 = Vb + (size_t)r1 * S + sswz;

  auto stage = [&](int buf) {
    __builtin_amdgcn_global_load_lds(
        (const __attribute__((address_space(1))) unsigned int*)ks0,
        (__attribute__((address_space(3))) unsigned int*)&Ks[buf][ci0 * 8], 16, 0, 0);
    __builtin_amdgcn_global_load_lds(
        (const __attribute__((address_space(1))) unsigned int*)ks1,
        (__attribute__((address_space(3))) unsigned int*)&Ks[buf][ci1 * 8], 16, 0, 0);
    __builtin_amdgcn_global_load_lds(
        (const __attribute__((address_space(1))) unsigned int*)vs0,
        (__attribute__((address_space(3))) unsigned int*)&Vs[buf][ci0 * 8], 16, 0, 0);
    __builtin_amdgcn_global_load_lds(
        (const __attribute__((address_space(1))) unsigned int*)vs1,
        (__attribute__((address_space(3))) unsigned int*)&Vs[buf][ci1 * 8], 16, 0, 0);
    ks0 += 4096; ks1 += 4096;
    vs0 += 64; vs1 += 64;
  };

  // one tile's full inner body (QK^T -> mask -> exp2/cvtpk -> PV + row-sum)
  auto tile_body = [&](const bf16x8* qg, f32x16* o, f32x16& ls, int qw, int kv0,
                       const unsigned short* K_, const unsigned short* V_) {
    f32x16 sacc[2] = {};
    __builtin_amdgcn_s_setprio(1);
#pragma unroll
    for (int kc = 0; kc < 4; ++kc) {
      bf16x8 kf0 = *reinterpret_cast<const bf16x8*>(
          &K_[l31 * 64 + ((2 * kc + hb) ^ x7) * 8]);
      bf16x8 kf1 = *reinterpret_cast<const bf16x8*>(
          &K_[(32 + l31) * 64 + ((2 * kc + hb) ^ x7) * 8]);
      sacc[0] = MFMA32(kf0, qg[kc], sacc[0]);
      sacc[1] = MFMA32(kf1, qg[kc], sacc[1]);
    }
    __builtin_amdgcn_s_setprio(0);
    if (kv0 + 63 > qw) {
      const int qrel = qw + l31 - kv0 - 8 * hb;
#pragma unroll
      for (int mi = 0; mi < 2; ++mi)
#pragma unroll
        for (int r = 0; r < 16; ++r) {
          int koff = (r & 7) + 16 * (r >> 3) + 32 * mi;
          if (koff > qrel) sacc[mi][r] = -1e30f;
        }
    }
    // exp2 + pack pairwise (keeps temp pressure low; no p[16] arrays)
    unsigned pw[2][8];
#pragma unroll
    for (int mi = 0; mi < 2; ++mi)
#pragma unroll
      for (int i = 0; i < 8; ++i) {
        float pa = __builtin_amdgcn_exp2f(sacc[mi][2 * i]);
        float pb = __builtin_amdgcn_exp2f(sacc[mi][2 * i + 1]);
        pw[mi][i] = cvtpk(pa, pb);
      }
    __builtin_amdgcn_s_setprio(1);
#pragma unroll
    for (int c = 0; c < 4; ++c) {
      union { unsigned u[4]; bf16x8 v; } pu;
      pu.u[0] = pw[c >> 1][(c & 1) * 4 + 0];
      pu.u[1] = pw[c >> 1][(c & 1) * 4 + 1];
      pu.u[2] = pw[c >> 1][(c & 1) * 4 + 2];
      pu.u[3] = pw[c >> 1][(c & 1) * 4 + 3];
#pragma unroll
      for (int db = 0; db < 2; ++db) {
        bf16x8 vf = *reinterpret_cast<const bf16x8*>(
            &V_[(32 * db + l31) * 64 + ((2 * c + hb) ^ x7) * 8]);
        o[db] = MFMA32(vf, pu.v, o[db]);
      }
      ls = MFMA32(ones, pu.v, ls);
    }
    __builtin_amdgcn_s_setprio(0);
  };

  stage(0);

  for (int it = 0; it < nt; ++it) {
    __syncthreads();  // staged tile [it] ready
    if (it + 1 < nt) stage((it + 1) & 1);
    const int kv0 = 64 * it;
    const unsigned short* K_ = Ks[it & 1];
    const unsigned short* V_ = Vs[it & 1];
    if (kv0 <= qwA + 31) tile_body(qgA, oA, lsA, qwA, kv0, K_, V_);
    if (kv0 <= qwB + 31) tile_body(qgB, oB, lsB, qwB, kv0, K_, V_);
  }

  // ---- epilogues: lane holds O^T[d = 32db+(r&3)+8(r>>2)+4hb][q = qw+l31] ----
  const int b = bh >> 4, h = bh & 15;
  {
    const float inv = 1.0f / lsA[0];
    unsigned short* cp = ctx + ((size_t)(b * 2048 + qwA + l31) * 1024) + h * 64;
#pragma unroll
    for (int db = 0; db < 2; ++db)
#pragma unroll
      for (int i = 0; i < 8; ++i) {
        unsigned w = cvtpk(oA[db][2 * i] * inv, oA[db][2 * i + 1] * inv);
        int d = 32 * db + ((2 * i) & 3) + 8 * (i >> 1) + 4 * hb;
        *reinterpret_cast<unsigned*>(cp + d) = w;
      }
  }
  {
    const float inv = 1.0f / lsB[0];
    unsigned short* cp = ctx + ((size_t)(b * 2048 + qwB + l31) * 1024) + h * 64;
#pragma unroll
    for (int db = 0; db < 2; ++db)
#pragma unroll
      for (int i = 0; i < 8; ++i) {
        unsigned w = cvtpk(oB[db][2 * i] * inv, oB[db][2 * i + 1] * inv);
        int d = 32 * db + ((2 * i) & 3) + 8 * (i >> 1) + 4 * hb;
        *reinterpret_cast<unsigned*>(cp + d) = w;
      }
  }
}

extern "C" void kernel_launch(void* const* d_in, const int* in_sizes, int n_in,
                              void* d_out, int out_size, void* d_ws, size_t ws_size,
                              hipStream_t stream) {
  const float* in_q = (const float*)d_in[0];
  const float* in_k = (const float*)d_in[1];
  const float* in_v = (const float*)d_in[2];
  const float* WQw = (const float*)d_in[3];
  const float* WQb = (const float*)d_in[4];
  const float* WKw = (const float*)d_in[5];
  const float* WKb = (const float*)d_in[6];
  const float* WVw = (const float*)d_in[7];
  const float* WVb = (const float*)d_in[8];
  const float* Ww  = (const float*)d_in[9];
  const float* Wb  = (const float*)d_in[10];
  float* out = (float*)d_out;

  constexpr size_t PROJ = (size_t)4 * 16 * 2048 * 64;  // 8,388,608 elems
  constexpr size_t WSZ = (size_t)1024 * 1024;
  const float qscale = 0.03125f * 1.4426950408889634f;  // 1/sqrt(1024) * log2(e)
  unsigned short* wsp = (unsigned short*)d_ws;

  const bool fused = ws_size >= (6 * PROJ + 4 * WSZ) * sizeof(unsigned short);

  if (fused) {
    unsigned short* Qp   = wsp;
    unsigned short* Kp   = wsp + PROJ;
    unsigned short* Vt   = wsp + 2 * PROJ;
    unsigned short* inq  = wsp + 3 * PROJ;  // later aliased as ctx
    unsigned short* ctx  = inq;
    unsigned short* ink  = wsp + 4 * PROJ;
    unsigned short* inv  = wsp + 5 * PROJ;
    unsigned short* wq16 = wsp + 6 * PROJ;
    unsigned short* wk16 = wq16 + WSZ;
    unsigned short* wv16 = wk16 + WSZ;
    unsigned short* ww16 = wv16 + WSZ;

    cvt_first_kernel<<<dim3(1024, 5), 256, 0, stream>>>(
        WQw, WKw, WVw, Ww, wq16, wk16, wv16, ww16, (int)(WSZ / 8),
        in_q, inq, (int)(PROJ / 8));
    gemm_kernel<0><<<2560, 256, 0, stream>>>(inq, wq16, WQb, Qp, 8192, 1024, 1024,
                                             qscale, 3, 512, in_k, ink, (int)(PROJ / 8));
    gemm_kernel<0><<<2560, 256, 0, stream>>>(ink, wk16, WKb, Kp, 8192, 1024, 1024,
                                             1.0f, 3, 512, in_v, inv, (int)(PROJ / 8));
    gemm_kernel<2><<<512, 256, 0, stream>>>(wv16, inv, WVb, Vt, 1024, 8192, 1024,
                                            1.0f, 6, 512, nullptr, nullptr, 0);
    attn8_kernel<<<512, 256, 0, stream>>>(Qp, Kp, Vt, ctx);
    gemm_kernel<1><<<512, 256, 0, stream>>>(ctx, ww16, Wb, out, 8192, 1024, 1024,
                                            1.0f, 3, 512, nullptr, nullptr, 0);
  } else {
    unsigned short* Qp   = wsp;
    unsigned short* Kp   = wsp + PROJ;
    unsigned short* Vt   = wsp + 2 * PROJ;
    unsigned short* in16 = wsp + 3 * PROJ;
    unsigned short* ctx  = in16;
    unsigned short* wq16 = wsp + 4 * PROJ;
    unsigned short* wk16 = wq16 + WSZ;
    unsigned short* wv16 = wk16 + WSZ;
    unsigned short* ww16 = wv16 + WSZ;

    cvt_first_kernel<<<dim3(1024, 5), 256, 0, stream>>>(
        WQw, WKw, WVw, Ww, wq16, wk16, wv16, ww16, (int)(WSZ / 8),
        in_q, in16, (int)(PROJ / 8));
    gemm_kernel<0><<<512, 256, 0, stream>>>(in16, wq16, WQb, Qp, 8192, 1024, 1024,
                                            qscale, 3, 512, nullptr, nullptr, 0);
    cvt1_kernel<<<2048, 256, 0, stream>>>(in_k, in16, (int)(PROJ / 8));
    gemm_kernel<0><<<512, 256, 0, stream>>>(in16, wk16, WKb, Kp, 8192, 1024, 1024,
                                            1.0f, 3, 512, nullptr, nullptr, 0);
    cvt1_kernel<<<2048, 256, 0, stream>>>(in_v, in16, (int)(PROJ / 8));
    gemm_kernel<2><<<512, 256, 0, stream>>>(wv16, in16, WVb, Vt, 1024, 8192, 1024,
                                            1.0f, 6, 512, nullptr, nullptr, 0);
    attn8_kernel<<<512, 256, 0, stream>>>(Qp, Kp, Vt, ctx);
    gemm_kernel<1><<<512, 256, 0, stream>>>(ctx, ww16, Wb, out, 8192, 1024, 1024,
                                            1.0f, 3, 512, nullptr, nullptr, 0);
  }
}

// Round 17
// 176.252 us; speedup vs baseline: 3.3766x; 1.2172x over previous
//
#include <hip/hip_runtime.h>
#include <hip/hip_bf16.h>

typedef __attribute__((ext_vector_type(8))) short bf16x8;
typedef __attribute__((ext_vector_type(4))) float f32x4;
typedef __attribute__((ext_vector_type(16))) float f32x16;
typedef __attribute__((ext_vector_type(4))) unsigned uint4v;

#define MFMA16(a, b, c) __builtin_amdgcn_mfma_f32_16x16x32_bf16(a, b, c, 0, 0, 0)
#define MFMA32(a, b, c) __builtin_amdgcn_mfma_f32_32x32x16_bf16(a, b, c, 0, 0, 0)

__device__ __forceinline__ unsigned short f2bfn(float f) {
#if defined(__gfx950__)
  __bf16 h = (__bf16)f;
  return __builtin_bit_cast(unsigned short, h);
#else
  union { float f; unsigned u; } x; x.f = f;
  unsigned r = x.u + 0x7fffu + ((x.u >> 16) & 1u);
  return (unsigned short)(r >> 16);
#endif
}

__device__ __forceinline__ unsigned cvtpk(float lo, float hi) {
  unsigned w;
  asm("v_cvt_pk_bf16_f32 %0, %1, %2" : "=v"(w) : "v"(lo), "v"(hi));
  return w;
}

// ---------------- fp32 -> bf16 conversion ----------------
__device__ __forceinline__ void cvt_range(const float* __restrict__ s,
                                          unsigned short* __restrict__ d,
                                          int i, int st, int n8) {
  for (; i < n8; i += st) {
    const float4* sp = reinterpret_cast<const float4*>(s) + 2 * (size_t)i;
    float4 a = sp[0], b = sp[1];
    uint4v o;
    o[0] = cvtpk(a.x, a.y); o[1] = cvtpk(a.z, a.w);
    o[2] = cvtpk(b.x, b.y); o[3] = cvtpk(b.z, b.w);
    reinterpret_cast<uint4v*>(d)[i] = o;
  }
}

__global__ void cvt1_kernel(const float* __restrict__ s, unsigned short* __restrict__ d, int n8) {
  cvt_range(s, d, blockIdx.x * blockDim.x + threadIdx.x, gridDim.x * blockDim.x, n8);
}

// y<4: weight matrices; y==4: Q input (larger, grid-strided)
__global__ void cvt_first_kernel(const float* s0, const float* s1, const float* s2,
                                 const float* s3, unsigned short* d0, unsigned short* d1,
                                 unsigned short* d2, unsigned short* d3, int wn8,
                                 const float* sq, unsigned short* dq, int qn8) {
  const float* s; unsigned short* d; int n8;
  switch (blockIdx.y) {
    case 0: s = s0; d = d0; n8 = wn8; break;
    case 1: s = s1; d = d1; n8 = wn8; break;
    case 2: s = s2; d = d2; n8 = wn8; break;
    case 3: s = s3; d = d3; n8 = wn8; break;
    default: s = sq; d = dq; n8 = qn8; break;
  }
  cvt_range(s, d, blockIdx.x * blockDim.x + threadIdx.x, gridDim.x * blockDim.x, n8);
}

// ---------------- GEMM (proven BK=64 config) ----------------
// 1D grid: n = sx & (2^nshift-1), m = sx >> nshift; nshift==3 gets the
// XCD-chunk swizzle: each XCD (bx%8) gets a contiguous 64-block chunk =
// 8 m-panels x 8 n-tiles -> unique working set/XCD = 2MB A-panels + 2MB
// full B = 4MB = L2 size. nshift==6 (V-gemm) keeps the natural map.
// Blocks with bx >= ngemm run an independent fp32->bf16 conversion (piggyback).
// MODE 0: bias[col], out bf16 scattered [B,H,S,64], *oscale
// MODE 1: bias[col], out fp32 row-major [M,N]
// MODE 2: bias[row], out bf16 V^T [BH,64,S]
template <int MODE>
__global__ __launch_bounds__(256) void gemm_kernel(
    const unsigned short* __restrict__ Av, const unsigned short* __restrict__ Bv,
    const float* __restrict__ bias, void* __restrict__ outv,
    int M, int N, int K, float oscale, int nshift, int ngemm,
    const float* __restrict__ csrc, unsigned short* __restrict__ cdst, int cn8) {
  constexpr int BM = 128, BN = 128, BK = 64;
  __shared__ __align__(16) unsigned short As[2][BM * BK];
  __shared__ __align__(16) unsigned short Bs[2][BN * BK];
  const int bx = blockIdx.x;
  const int tid = threadIdx.x;
  if (bx >= ngemm) {
    cvt_range(csrc, cdst, (bx - ngemm) * blockDim.x + tid,
              (gridDim.x - ngemm) * blockDim.x, cn8);
    return;
  }
  int sx = bx;
  if (nshift == 3) sx = (bx & 7) * (ngemm >> 3) + (bx >> 3);
  const int lane = tid & 63, wave = tid >> 6;
  const int wr = wave >> 1, wc = wave & 1;
  const int m0 = (sx >> nshift) * BM, n0 = (sx & ((1 << nshift) - 1)) * BN;
  const int rb = lane & 15, g = lane >> 4;
  const int swz = ((lane & 7) ^ ((lane >> 3) & 7)) * 8;
  f32x4 acc[4][4] = {};

  const unsigned short* Ab = Av + (size_t)m0 * K;
  const unsigned short* Bb = Bv + (size_t)n0 * K;

  auto stage = [&](int buf, int k0) {
#pragma unroll
    for (int i = 0; i < 4; ++i) {
      const int c = wave * 256 + i * 64 + lane;
      const int r = c >> 3;
      __builtin_amdgcn_global_load_lds(
          (const __attribute__((address_space(1))) unsigned int*)(Ab + (size_t)r * K + k0 + swz),
          (__attribute__((address_space(3))) unsigned int*)&As[buf][c * 8], 16, 0, 0);
      __builtin_amdgcn_global_load_lds(
          (const __attribute__((address_space(1))) unsigned int*)(Bb + (size_t)r * K + k0 + swz),
          (__attribute__((address_space(3))) unsigned int*)&Bs[buf][c * 8], 16, 0, 0);
    }
  };

  const int nt = K / BK;
  stage(0, 0);
  int cur = 0;
  for (int t = 0; t < nt; ++t) {
    __syncthreads();
    if (t + 1 < nt) stage(cur ^ 1, (t + 1) * BK);
    const unsigned short* A_ = As[cur];
    const unsigned short* B_ = Bs[cur];
#pragma unroll
    for (int kc = 0; kc < 2; ++kc) {
      bf16x8 af[4], bfr[4];
#pragma unroll
      for (int mi = 0; mi < 4; ++mi)
        af[mi] = *reinterpret_cast<const bf16x8*>(
            &A_[(wr * 64 + mi * 16 + rb) * 64 + (((kc * 4 + g) ^ (rb & 7)) * 8)]);
#pragma unroll
      for (int ni = 0; ni < 4; ++ni)
        bfr[ni] = *reinterpret_cast<const bf16x8*>(
            &B_[(wc * 64 + ni * 16 + rb) * 64 + (((kc * 4 + g) ^ (rb & 7)) * 8)]);
#pragma unroll
      for (int mi = 0; mi < 4; ++mi)
#pragma unroll
        for (int ni = 0; ni < 4; ++ni)
          acc[mi][ni] = MFMA16(af[mi], bfr[ni], acc[mi][ni]);
    }
    cur ^= 1;
  }

#pragma unroll
  for (int mi = 0; mi < 4; ++mi) {
#pragma unroll
    for (int ni = 0; ni < 4; ++ni) {
      int col = n0 + wc * 64 + ni * 16 + rb;
      if constexpr (MODE != 2) {
        float bvv = bias[col];
#pragma unroll
        for (int j = 0; j < 4; ++j) {
          int row = m0 + wr * 64 + mi * 16 + g * 4 + j;
          float v = acc[mi][ni][j] + bvv;
          if constexpr (MODE == 0) {
            v *= oscale;
            int b = row >> 11, s = row & 2047;
            int h = col >> 6, e = col & 63;
            ((unsigned short*)outv)[((size_t)(b * 16 + h) * 2048 + s) * 64 + e] = f2bfn(v);
          } else {
            ((float*)outv)[(size_t)row * N + col] = v;
          }
        }
      } else {
        int bb = col >> 11, s = col & 2047;
#pragma unroll
        for (int j = 0; j < 4; ++j) {
          int row = m0 + wr * 64 + mi * 16 + g * 4 + j;
          float v = acc[mi][ni][j] + bias[row];
          int h = row >> 6, e = row & 63;
          ((unsigned short*)outv)[((size_t)(bb * 16 + h) * 64 + e) * 2048 + s] = f2bfn(v);
        }
      }
    }
  }
}

// ---------------- flash attention (round-12 proven) ----------------
// 32x32 swapped, NO-MAX softmax (logits provably bounded; scale folded into Q
// projection), MFMA row-sum via ones-A, swap23 K-row permutation so the QK^T
// output lands exactly where PV's B-fragment consumes it (zero cross-lane ops).
__global__ __launch_bounds__(256) void attn7_kernel(
    const unsigned short* __restrict__ Qp, const unsigned short* __restrict__ Kp,
    const unsigned short* __restrict__ Vtp, unsigned short* __restrict__ ctx) {
  constexpr int S = 2048;
  __shared__ __align__(16) unsigned short Ks[2][64 * 64];
  __shared__ __align__(16) unsigned short Vs[2][64 * 64];
  const int bx = blockIdx.x;
  const int bh = bx & 63;
  const int qti = 15 - (bx >> 6);  // heavy tiles first
  const int tid = threadIdx.x, wave = tid >> 6, lane = tid & 63;
  const int l31 = lane & 31, hb = lane >> 5;
  const int x7 = l31 & 7;
  const int qw = qti * 128 + wave * 32;
  const unsigned short* Qb = Qp + (size_t)bh * S * 64;
  const unsigned short* Kb = Kp + (size_t)bh * S * 64;
  const unsigned short* Vb = Vtp + (size_t)bh * 64 * S;

  bf16x8 qg[4];
#pragma unroll
  for (int kc = 0; kc < 4; ++kc)
    qg[kc] = *reinterpret_cast<const bf16x8*>(
        Qb + (size_t)(qw + l31) * 64 + 16 * kc + 8 * hb);

  bf16x8 ones;
#pragma unroll
  for (int i = 0; i < 8; ++i) ones[i] = (short)0x3F80;

  f32x16 ls = {};
  f32x16 o[2] = {};
  const int sswz = ((lane & 7) ^ (lane >> 3)) * 8;
  const int nt = qti * 2 + 2;

  const int ci0 = wave * 2 * 64 + lane, ci1 = ci0 + 64;
  const int r0 = wave * 16 + (lane >> 3), r1 = r0 + 8;
  const int rs0 = (r0 & 51) | ((r0 & 4) << 1) | ((r0 & 8) >> 1);
  const int rs1 = (r1 & 51) | ((r1 & 4) << 1) | ((r1 & 8) >> 1);
  const unsigned short* ks0 = Kb + (size_t)rs0 * 64 + sswz;
  const unsigned short* ks1 = Kb + (size_t)rs1 * 64 + sswz;
  const unsigned short* vs0 = Vb + (size_t)r0 * S + sswz;
  const unsigned short* vs1 = Vb + (size_t)r1 * S + sswz;

  auto stage = [&](int buf) {
    __builtin_amdgcn_global_load_lds(
        (const __attribute__((address_space(1))) unsigned int*)ks0,
        (__attribute__((address_space(3))) unsigned int*)&Ks[buf][ci0 * 8], 16, 0, 0);
    __builtin_amdgcn_global_load_lds(
        (const __attribute__((address_space(1))) unsigned int*)ks1,
        (__attribute__((address_space(3))) unsigned int*)&Ks[buf][ci1 * 8], 16, 0, 0);
    __builtin_amdgcn_global_load_lds(
        (const __attribute__((address_space(1))) unsigned int*)vs0,
        (__attribute__((address_space(3))) unsigned int*)&Vs[buf][ci0 * 8], 16, 0, 0);
    __builtin_amdgcn_global_load_lds(
        (const __attribute__((address_space(1))) unsigned int*)vs1,
        (__attribute__((address_space(3))) unsigned int*)&Vs[buf][ci1 * 8], 16, 0, 0);
    ks0 += 4096; ks1 += 4096;
    vs0 += 64; vs1 += 64;
  };

  stage(0);

  for (int it = 0; it < nt; ++it) {
    __syncthreads();
    if (it + 1 < nt) stage((it + 1) & 1);
    const int kv0 = 64 * it;
    if (kv0 <= qw + 31) {
      const unsigned short* K_ = Ks[it & 1];
      const unsigned short* V_ = Vs[it & 1];
      f32x16 sacc[2] = {};
      __builtin_amdgcn_s_setprio(1);
#pragma unroll
      for (int kc = 0; kc < 4; ++kc) {
        bf16x8 kf0 = *reinterpret_cast<const bf16x8*>(
            &K_[l31 * 64 + ((2 * kc + hb) ^ x7) * 8]);
        bf16x8 kf1 = *reinterpret_cast<const bf16x8*>(
            &K_[(32 + l31) * 64 + ((2 * kc + hb) ^ x7) * 8]);
        sacc[0] = MFMA32(kf0, qg[kc], sacc[0]);
        sacc[1] = MFMA32(kf1, qg[kc], sacc[1]);
      }
      __builtin_amdgcn_s_setprio(0);
      if (kv0 + 63 > qw) {
        const int qrel = qw + l31 - kv0 - 8 * hb;
#pragma unroll
        for (int mi = 0; mi < 2; ++mi)
#pragma unroll
          for (int r = 0; r < 16; ++r) {
            int koff = (r & 7) + 16 * (r >> 3) + 32 * mi;
            if (koff > qrel) sacc[mi][r] = -1e30f;
          }
      }
      float p0[16], p1[16];
#pragma unroll
      for (int r = 0; r < 16; ++r) p0[r] = __builtin_amdgcn_exp2f(sacc[0][r]);
#pragma unroll
      for (int r = 0; r < 16; ++r) p1[r] = __builtin_amdgcn_exp2f(sacc[1][r]);
      unsigned pw[2][8];
#pragma unroll
      for (int i = 0; i < 8; ++i) pw[0][i] = cvtpk(p0[2 * i], p0[2 * i + 1]);
#pragma unroll
      for (int i = 0; i < 8; ++i) pw[1][i] = cvtpk(p1[2 * i], p1[2 * i + 1]);
      __builtin_amdgcn_s_setprio(1);
#pragma unroll
      for (int c = 0; c < 4; ++c) {
        union { unsigned u[4]; bf16x8 v; } pu;
        pu.u[0] = pw[c >> 1][(c & 1) * 4 + 0];
        pu.u[1] = pw[c >> 1][(c & 1) * 4 + 1];
        pu.u[2] = pw[c >> 1][(c & 1) * 4 + 2];
        pu.u[3] = pw[c >> 1][(c & 1) * 4 + 3];
#pragma unroll
        for (int db = 0; db < 2; ++db) {
          bf16x8 vf = *reinterpret_cast<const bf16x8*>(
              &V_[(32 * db + l31) * 64 + ((2 * c + hb) ^ x7) * 8]);
          o[db] = MFMA32(vf, pu.v, o[db]);
        }
        ls = MFMA32(ones, pu.v, ls);
      }
      __builtin_amdgcn_s_setprio(0);
    }
  }

  const float inv = 1.0f / ls[0];
  const int b = bh >> 4, h = bh & 15;
  const int q = qw + l31;
  unsigned short* cp = ctx + ((size_t)(b * 2048 + q) * 1024) + h * 64;
#pragma unroll
  for (int db = 0; db < 2; ++db)
#pragma unroll
    for (int i = 0; i < 8; ++i) {
      unsigned w = cvtpk(o[db][2 * i] * inv, o[db][2 * i + 1] * inv);
      int d = 32 * db + ((2 * i) & 3) + 8 * (i >> 1) + 4 * hb;
      *reinterpret_cast<unsigned*>(cp + d) = w;
    }
}

extern "C" void kernel_launch(void* const* d_in, const int* in_sizes, int n_in,
                              void* d_out, int out_size, void* d_ws, size_t ws_size,
                              hipStream_t stream) {
  const float* in_q = (const float*)d_in[0];
  const float* in_k = (const float*)d_in[1];
  const float* in_v = (const float*)d_in[2];
  const float* WQw = (const float*)d_in[3];
  const float* WQb = (const float*)d_in[4];
  const float* WKw = (const float*)d_in[5];
  const float* WKb = (const float*)d_in[6];
  const float* WVw = (const float*)d_in[7];
  const float* WVb = (const float*)d_in[8];
  const float* Ww  = (const float*)d_in[9];
  const float* Wb  = (const float*)d_in[10];
  float* out = (float*)d_out;

  constexpr size_t PROJ = (size_t)4 * 16 * 2048 * 64;  // 8,388,608 elems
  constexpr size_t WSZ = (size_t)1024 * 1024;
  const float qscale = 0.03125f * 1.4426950408889634f;  // 1/sqrt(1024) * log2(e)
  unsigned short* wsp = (unsigned short*)d_ws;

  const bool fused = ws_size >= (6 * PROJ + 4 * WSZ) * sizeof(unsigned short);

  if (fused) {
    unsigned short* Qp   = wsp;
    unsigned short* Kp   = wsp + PROJ;
    unsigned short* Vt   = wsp + 2 * PROJ;
    unsigned short* inq  = wsp + 3 * PROJ;  // later aliased as ctx
    unsigned short* ctx  = inq;
    unsigned short* ink  = wsp + 4 * PROJ;
    unsigned short* inv  = wsp + 5 * PROJ;
    unsigned short* wq16 = wsp + 6 * PROJ;
    unsigned short* wk16 = wq16 + WSZ;
    unsigned short* wv16 = wk16 + WSZ;
    unsigned short* ww16 = wv16 + WSZ;

    // weights + Q input -> bf16 (one launch)
    cvt_first_kernel<<<dim3(1024, 5), 256, 0, stream>>>(
        WQw, WKw, WVw, Ww, wq16, wk16, wv16, ww16, (int)(WSZ / 8),
        in_q, inq, (int)(PROJ / 8));
    // Q projection; cvt of K input hidden in the same dispatch
    gemm_kernel<0><<<2560, 256, 0, stream>>>(inq, wq16, WQb, Qp, 8192, 1024, 1024,
                                             qscale, 3, 512, in_k, ink, (int)(PROJ / 8));
    // K projection; cvt of V input hidden
    gemm_kernel<0><<<2560, 256, 0, stream>>>(ink, wk16, WKb, Kp, 8192, 1024, 1024,
                                             1.0f, 3, 512, in_v, inv, (int)(PROJ / 8));
    // V projection computed transposed -> V^T [B*H, 64, S]
    gemm_kernel<2><<<512, 256, 0, stream>>>(wv16, inv, WVb, Vt, 1024, 8192, 1024,
                                            1.0f, 6, 512, nullptr, nullptr, 0);
    attn7_kernel<<<1024, 256, 0, stream>>>(Qp, Kp, Vt, ctx);
    gemm_kernel<1><<<512, 256, 0, stream>>>(ctx, ww16, Wb, out, 8192, 1024, 1024,
                                            1.0f, 3, 512, nullptr, nullptr, 0);
  } else {
    // serial fallback (in16 reused q->k->v, aliased as ctx)
    unsigned short* Qp   = wsp;
    unsigned short* Kp   = wsp + PROJ;
    unsigned short* Vt   = wsp + 2 * PROJ;
    unsigned short* in16 = wsp + 3 * PROJ;
    unsigned short* ctx  = in16;
    unsigned short* wq16 = wsp + 4 * PROJ;
    unsigned short* wk16 = wq16 + WSZ;
    unsigned short* wv16 = wk16 + WSZ;
    unsigned short* ww16 = wv16 + WSZ;

    cvt_first_kernel<<<dim3(1024, 5), 256, 0, stream>>>(
        WQw, WKw, WVw, Ww, wq16, wk16, wv16, ww16, (int)(WSZ / 8),
        in_q, in16, (int)(PROJ / 8));
    gemm_kernel<0><<<512, 256, 0, stream>>>(in16, wq16, WQb, Qp, 8192, 1024, 1024,
                                            qscale, 3, 512, nullptr, nullptr, 0);
    cvt1_kernel<<<2048, 256, 0, stream>>>(in_k, in16, (int)(PROJ / 8));
    gemm_kernel<0><<<512, 256, 0, stream>>>(in16, wk16, WKb, Kp, 8192, 1024, 1024,
                                            1.0f, 3, 512, nullptr, nullptr, 0);
    cvt1_kernel<<<2048, 256, 0, stream>>>(in_v, in16, (int)(PROJ / 8));
    gemm_kernel<2><<<512, 256, 0, stream>>>(wv16, in16, WVb, Vt, 1024, 8192, 1024,
                                            1.0f, 6, 512, nullptr, nullptr, 0);
    attn7_kernel<<<1024, 256, 0, stream>>>(Qp, Kp, Vt, ctx);
    gemm_kernel<1><<<512, 256, 0, stream>>>(ctx, ww16, Wb, out, 8192, 1024, 1024,
                                            1.0f, 3, 512, nullptr, nullptr, 0);
  }
}

// Round 18
// 168.973 us; speedup vs baseline: 3.5221x; 1.0431x over previous
//
#include <hip/hip_runtime.h>
#include <hip/hip_bf16.h>

typedef __attribute__((ext_vector_type(8))) short bf16x8;
typedef __attribute__((ext_vector_type(4))) float f32x4;
typedef __attribute__((ext_vector_type(16))) float f32x16;
typedef __attribute__((ext_vector_type(4))) unsigned uint4v;

#define MFMA16(a, b, c) __builtin_amdgcn_mfma_f32_16x16x32_bf16(a, b, c, 0, 0, 0)
#define MFMA32(a, b, c) __builtin_amdgcn_mfma_f32_32x32x16_bf16(a, b, c, 0, 0, 0)

__device__ __forceinline__ unsigned short f2bfn(float f) {
#if defined(__gfx950__)
  __bf16 h = (__bf16)f;
  return __builtin_bit_cast(unsigned short, h);
#else
  union { float f; unsigned u; } x; x.f = f;
  unsigned r = x.u + 0x7fffu + ((x.u >> 16) & 1u);
  return (unsigned short)(r >> 16);
#endif
}

__device__ __forceinline__ unsigned cvtpk(float lo, float hi) {
  unsigned w;
  asm("v_cvt_pk_bf16_f32 %0, %1, %2" : "=v"(w) : "v"(lo), "v"(hi));
  return w;
}

// ---------------- fp32 -> bf16 conversion ----------------
__device__ __forceinline__ void cvt_range(const float* __restrict__ s,
                                          unsigned short* __restrict__ d,
                                          int i, int st, int n8) {
  for (; i < n8; i += st) {
    const float4* sp = reinterpret_cast<const float4*>(s) + 2 * (size_t)i;
    float4 a = sp[0], b = sp[1];
    uint4v o;
    o[0] = cvtpk(a.x, a.y); o[1] = cvtpk(a.z, a.w);
    o[2] = cvtpk(b.x, b.y); o[3] = cvtpk(b.z, b.w);
    reinterpret_cast<uint4v*>(d)[i] = o;
  }
}

__global__ void cvt1_kernel(const float* __restrict__ s, unsigned short* __restrict__ d, int n8) {
  cvt_range(s, d, blockIdx.x * blockDim.x + threadIdx.x, gridDim.x * blockDim.x, n8);
}

// y<4: weight matrices; y==4: Q input (larger, grid-strided)
__global__ void cvt_first_kernel(const float* s0, const float* s1, const float* s2,
                                 const float* s3, unsigned short* d0, unsigned short* d1,
                                 unsigned short* d2, unsigned short* d3, int wn8,
                                 const float* sq, unsigned short* dq, int qn8) {
  const float* s; unsigned short* d; int n8;
  switch (blockIdx.y) {
    case 0: s = s0; d = d0; n8 = wn8; break;
    case 1: s = s1; d = d1; n8 = wn8; break;
    case 2: s = s2; d = d2; n8 = wn8; break;
    case 3: s = s3; d = d3; n8 = wn8; break;
    default: s = sq; d = dq; n8 = qn8; break;
  }
  cvt_range(s, d, blockIdx.x * blockDim.x + threadIdx.x, gridDim.x * blockDim.x, n8);
}

// ---------------- GEMM (proven BK=64 config) ----------------
// 1D grid: n = sx & (2^nshift-1), m = sx >> nshift; nshift==3 gets the
// XCD-chunk swizzle (4MB working set per XCD). Blocks bx >= ngemm piggyback cvt.
// MODE 0: bias[col], out bf16 scattered [B,H,S,64], *oscale
// MODE 1: bias[col], out fp32 row-major [M,N]
// MODE 2: bias[row], out bf16 V^T [BH,64,S]
template <int MODE>
__global__ __launch_bounds__(256) void gemm_kernel(
    const unsigned short* __restrict__ Av, const unsigned short* __restrict__ Bv,
    const float* __restrict__ bias, void* __restrict__ outv,
    int M, int N, int K, float oscale, int nshift, int ngemm,
    const float* __restrict__ csrc, unsigned short* __restrict__ cdst, int cn8) {
  constexpr int BM = 128, BN = 128, BK = 64;
  __shared__ __align__(16) unsigned short As[2][BM * BK];
  __shared__ __align__(16) unsigned short Bs[2][BN * BK];
  const int bx = blockIdx.x;
  const int tid = threadIdx.x;
  if (bx >= ngemm) {
    cvt_range(csrc, cdst, (bx - ngemm) * blockDim.x + tid,
              (gridDim.x - ngemm) * blockDim.x, cn8);
    return;
  }
  int sx = bx;
  if (nshift == 3) sx = (bx & 7) * (ngemm >> 3) + (bx >> 3);
  const int lane = tid & 63, wave = tid >> 6;
  const int wr = wave >> 1, wc = wave & 1;
  const int m0 = (sx >> nshift) * BM, n0 = (sx & ((1 << nshift) - 1)) * BN;
  const int rb = lane & 15, g = lane >> 4;
  const int swz = ((lane & 7) ^ ((lane >> 3) & 7)) * 8;
  f32x4 acc[4][4] = {};

  const unsigned short* Ab = Av + (size_t)m0 * K;
  const unsigned short* Bb = Bv + (size_t)n0 * K;

  auto stage = [&](int buf, int k0) {
#pragma unroll
    for (int i = 0; i < 4; ++i) {
      const int c = wave * 256 + i * 64 + lane;
      const int r = c >> 3;
      __builtin_amdgcn_global_load_lds(
          (const __attribute__((address_space(1))) unsigned int*)(Ab + (size_t)r * K + k0 + swz),
          (__attribute__((address_space(3))) unsigned int*)&As[buf][c * 8], 16, 0, 0);
      __builtin_amdgcn_global_load_lds(
          (const __attribute__((address_space(1))) unsigned int*)(Bb + (size_t)r * K + k0 + swz),
          (__attribute__((address_space(3))) unsigned int*)&Bs[buf][c * 8], 16, 0, 0);
    }
  };

  const int nt = K / BK;
  stage(0, 0);
  int cur = 0;
  for (int t = 0; t < nt; ++t) {
    __syncthreads();
    if (t + 1 < nt) stage(cur ^ 1, (t + 1) * BK);
    const unsigned short* A_ = As[cur];
    const unsigned short* B_ = Bs[cur];
#pragma unroll
    for (int kc = 0; kc < 2; ++kc) {
      bf16x8 af[4], bfr[4];
#pragma unroll
      for (int mi = 0; mi < 4; ++mi)
        af[mi] = *reinterpret_cast<const bf16x8*>(
            &A_[(wr * 64 + mi * 16 + rb) * 64 + (((kc * 4 + g) ^ (rb & 7)) * 8)]);
#pragma unroll
      for (int ni = 0; ni < 4; ++ni)
        bfr[ni] = *reinterpret_cast<const bf16x8*>(
            &B_[(wc * 64 + ni * 16 + rb) * 64 + (((kc * 4 + g) ^ (rb & 7)) * 8)]);
#pragma unroll
      for (int mi = 0; mi < 4; ++mi)
#pragma unroll
        for (int ni = 0; ni < 4; ++ni)
          acc[mi][ni] = MFMA16(af[mi], bfr[ni], acc[mi][ni]);
    }
    cur ^= 1;
  }

#pragma unroll
  for (int mi = 0; mi < 4; ++mi) {
#pragma unroll
    for (int ni = 0; ni < 4; ++ni) {
      int col = n0 + wc * 64 + ni * 16 + rb;
      if constexpr (MODE != 2) {
        float bvv = bias[col];
#pragma unroll
        for (int j = 0; j < 4; ++j) {
          int row = m0 + wr * 64 + mi * 16 + g * 4 + j;
          float v = acc[mi][ni][j] + bvv;
          if constexpr (MODE == 0) {
            v *= oscale;
            int b = row >> 11, s = row & 2047;
            int h = col >> 6, e = col & 63;
            ((unsigned short*)outv)[((size_t)(b * 16 + h) * 2048 + s) * 64 + e] = f2bfn(v);
          } else {
            ((float*)outv)[(size_t)row * N + col] = v;
          }
        }
      } else {
        int bb = col >> 11, s = col & 2047;
#pragma unroll
        for (int j = 0; j < 4; ++j) {
          int row = m0 + wr * 64 + mi * 16 + g * 4 + j;
          float v = acc[mi][ni][j] + bias[row];
          int h = row >> 6, e = row & 63;
          ((unsigned short*)outv)[((size_t)(bb * 16 + h) * 64 + e) * 2048 + s] = f2bfn(v);
        }
      }
    }
  }
}

// ---------------- flash attention: T15 double-pipeline over the proven attn7 body ----------------
// 3 LDS buffers, 2-deep prefetch with counted vmcnt(4); per sub-iter: QK^T of
// tile t issues BEFORE the softmax-finish+PV of tile t-1 (intra-wave MFMA||VALU
// overlap). Second barrier only before a stage call (its target buffer is the
// V-buffer that finish just read). Loop unrolled x2 (nt even) with named sA/sB.
__global__ __launch_bounds__(256) void attn9_kernel(
    const unsigned short* __restrict__ Qp, const unsigned short* __restrict__ Kp,
    const unsigned short* __restrict__ Vtp, unsigned short* __restrict__ ctx) {
  constexpr int S = 2048;
  __shared__ __align__(16) unsigned short Ks[3][64 * 64];
  __shared__ __align__(16) unsigned short Vs[3][64 * 64];
  const int bx = blockIdx.x;
  const int bh = bx & 63;
  const int qti = 15 - (bx >> 6);  // heavy tiles first
  const int tid = threadIdx.x, wave = tid >> 6, lane = tid & 63;
  const int l31 = lane & 31, hb = lane >> 5;
  const int x7 = l31 & 7;
  const int qw = qti * 128 + wave * 32;
  const unsigned short* Qb = Qp + (size_t)bh * S * 64;
  const unsigned short* Kb = Kp + (size_t)bh * S * 64;
  const unsigned short* Vb = Vtp + (size_t)bh * 64 * S;

  bf16x8 qg[4];
#pragma unroll
  for (int kc = 0; kc < 4; ++kc)
    qg[kc] = *reinterpret_cast<const bf16x8*>(
        Qb + (size_t)(qw + l31) * 64 + 16 * kc + 8 * hb);

  bf16x8 ones;
#pragma unroll
  for (int i = 0; i < 8; ++i) ones[i] = (short)0x3F80;

  f32x16 ls = {};
  f32x16 o[2] = {};
  const int sswz = ((lane & 7) ^ (lane >> 3)) * 8;
  const int nt = qti * 2 + 2;  // always even

  const int ci0 = wave * 2 * 64 + lane, ci1 = ci0 + 64;
  const int r0 = wave * 16 + (lane >> 3), r1 = r0 + 8;
  const int rs0 = (r0 & 51) | ((r0 & 4) << 1) | ((r0 & 8) >> 1);
  const int rs1 = (r1 & 51) | ((r1 & 4) << 1) | ((r1 & 8) >> 1);
  const unsigned short* ks0 = Kb + (size_t)rs0 * 64 + sswz;
  const unsigned short* ks1 = Kb + (size_t)rs1 * 64 + sswz;
  const unsigned short* vs0 = Vb + (size_t)r0 * S + sswz;
  const unsigned short* vs1 = Vb + (size_t)r1 * S + sswz;

  auto stage = [&](int buf) {
    __builtin_amdgcn_global_load_lds(
        (const __attribute__((address_space(1))) unsigned int*)ks0,
        (__attribute__((address_space(3))) unsigned int*)&Ks[buf][ci0 * 8], 16, 0, 0);
    __builtin_amdgcn_global_load_lds(
        (const __attribute__((address_space(1))) unsigned int*)ks1,
        (__attribute__((address_space(3))) unsigned int*)&Ks[buf][ci1 * 8], 16, 0, 0);
    __builtin_amdgcn_global_load_lds(
        (const __attribute__((address_space(1))) unsigned int*)vs0,
        (__attribute__((address_space(3))) unsigned int*)&Vs[buf][ci0 * 8], 16, 0, 0);
    __builtin_amdgcn_global_load_lds(
        (const __attribute__((address_space(1))) unsigned int*)vs1,
        (__attribute__((address_space(3))) unsigned int*)&Vs[buf][ci1 * 8], 16, 0, 0);
    ks0 += 4096; ks1 += 4096;  // +64 K-rows
    vs0 += 64; vs1 += 64;      // +64 kv-cols
  };

  // QK^T of one tile -> sacc[2] (raw, pre-scaled logits; causal mask applied)
  auto qkt = [&](f32x16* sacc, const unsigned short* K_, int kv0) {
    sacc[0] = f32x16{};
    sacc[1] = f32x16{};
    __builtin_amdgcn_s_setprio(1);
#pragma unroll
    for (int kc = 0; kc < 4; ++kc) {
      bf16x8 kf0 = *reinterpret_cast<const bf16x8*>(
          &K_[l31 * 64 + ((2 * kc + hb) ^ x7) * 8]);
      bf16x8 kf1 = *reinterpret_cast<const bf16x8*>(
          &K_[(32 + l31) * 64 + ((2 * kc + hb) ^ x7) * 8]);
      sacc[0] = MFMA32(kf0, qg[kc], sacc[0]);
      sacc[1] = MFMA32(kf1, qg[kc], sacc[1]);
    }
    __builtin_amdgcn_s_setprio(0);
    if (kv0 + 63 > qw) {
      const int qrel = qw + l31 - kv0 - 8 * hb;
#pragma unroll
      for (int mi = 0; mi < 2; ++mi)
#pragma unroll
        for (int r = 0; r < 16; ++r) {
          int koff = (r & 7) + 16 * (r >> 3) + 32 * mi;
          if (koff > qrel) sacc[mi][r] = -1e30f;
        }
    }
  };

  // softmax-finish + PV + row-sum for a previously computed tile
  auto finish = [&](const f32x16* sacc, const unsigned short* V_) {
    unsigned pw[2][8];
#pragma unroll
    for (int mi = 0; mi < 2; ++mi)
#pragma unroll
      for (int i = 0; i < 8; ++i) {
        float pa = __builtin_amdgcn_exp2f(sacc[mi][2 * i]);
        float pb = __builtin_amdgcn_exp2f(sacc[mi][2 * i + 1]);
        pw[mi][i] = cvtpk(pa, pb);
      }
    __builtin_amdgcn_s_setprio(1);
#pragma unroll
    for (int c = 0; c < 4; ++c) {
      union { unsigned u[4]; bf16x8 v; } pu;
      pu.u[0] = pw[c >> 1][(c & 1) * 4 + 0];
      pu.u[1] = pw[c >> 1][(c & 1) * 4 + 1];
      pu.u[2] = pw[c >> 1][(c & 1) * 4 + 2];
      pu.u[3] = pw[c >> 1][(c & 1) * 4 + 3];
#pragma unroll
      for (int db = 0; db < 2; ++db) {
        bf16x8 vf = *reinterpret_cast<const bf16x8*>(
            &V_[(32 * db + l31) * 64 + ((2 * c + hb) ^ x7) * 8]);
        o[db] = MFMA32(vf, pu.v, o[db]);
      }
      ls = MFMA32(ones, pu.v, ls);
    }
    __builtin_amdgcn_s_setprio(0);
  };

  stage(0);
  stage(1);

  f32x16 sA[2], sB[2];

  for (int it = 0; it < nt; it += 2) {
    // ---- even sub-iter: QKT(it) -> sA ; finish(it-1) from sB ----
    if (it < nt - 1) asm volatile("s_waitcnt vmcnt(4)" ::: "memory");
    else             asm volatile("s_waitcnt vmcnt(0)" ::: "memory");
    __builtin_amdgcn_s_barrier();
    __builtin_amdgcn_sched_barrier(0);
    {
      const int kv0 = 64 * it;
      if (kv0 <= qw + 31) qkt(sA, Ks[it % 3], kv0);
      if (it > 0 && kv0 - 64 <= qw + 31) finish(sB, Vs[(it - 1) % 3]);
      if (it + 2 < nt) {
        __builtin_amdgcn_s_barrier();  // all waves done reading buffer (it-1)%3
        __builtin_amdgcn_sched_barrier(0);
        stage((it + 2) % 3);
      }
    }
    // ---- odd sub-iter: QKT(it+1) -> sB ; finish(it) from sA ----
    const int it1 = it + 1;
    if (it1 < nt - 1) asm volatile("s_waitcnt vmcnt(4)" ::: "memory");
    else              asm volatile("s_waitcnt vmcnt(0)" ::: "memory");
    __builtin_amdgcn_s_barrier();
    __builtin_amdgcn_sched_barrier(0);
    {
      const int kv0 = 64 * it1;
      if (kv0 <= qw + 31) qkt(sB, Ks[it1 % 3], kv0);
      if (kv0 - 64 <= qw + 31) finish(sA, Vs[it % 3]);
      if (it1 + 2 < nt) {
        __builtin_amdgcn_s_barrier();
        __builtin_amdgcn_sched_barrier(0);
        stage((it1 + 2) % 3);
      }
    }
  }
  // drain: finish last tile (nt-1, held in sB)
  if (64 * (nt - 1) <= qw + 31) finish(sB, Vs[(nt - 1) % 3]);

  // ---- epilogue: lane holds O^T[d = 32db+(r&3)+8(r>>2)+4hb][q = qw+l31] ----
  const float inv = 1.0f / ls[0];
  const int b = bh >> 4, h = bh & 15;
  const int q = qw + l31;
  unsigned short* cp = ctx + ((size_t)(b * 2048 + q) * 1024) + h * 64;
#pragma unroll
  for (int db = 0; db < 2; ++db)
#pragma unroll
    for (int i = 0; i < 8; ++i) {
      unsigned w = cvtpk(o[db][2 * i] * inv, o[db][2 * i + 1] * inv);
      int d = 32 * db + ((2 * i) & 3) + 8 * (i >> 1) + 4 * hb;
      *reinterpret_cast<unsigned*>(cp + d) = w;
    }
}

extern "C" void kernel_launch(void* const* d_in, const int* in_sizes, int n_in,
                              void* d_out, int out_size, void* d_ws, size_t ws_size,
                              hipStream_t stream) {
  const float* in_q = (const float*)d_in[0];
  const float* in_k = (const float*)d_in[1];
  const float* in_v = (const float*)d_in[2];
  const float* WQw = (const float*)d_in[3];
  const float* WQb = (const float*)d_in[4];
  const float* WKw = (const float*)d_in[5];
  const float* WKb = (const float*)d_in[6];
  const float* WVw = (const float*)d_in[7];
  const float* WVb = (const float*)d_in[8];
  const float* Ww  = (const float*)d_in[9];
  const float* Wb  = (const float*)d_in[10];
  float* out = (float*)d_out;

  constexpr size_t PROJ = (size_t)4 * 16 * 2048 * 64;  // 8,388,608 elems
  constexpr size_t WSZ = (size_t)1024 * 1024;
  const float qscale = 0.03125f * 1.4426950408889634f;  // 1/sqrt(1024) * log2(e)
  unsigned short* wsp = (unsigned short*)d_ws;

  const bool fused = ws_size >= (6 * PROJ + 4 * WSZ) * sizeof(unsigned short);

  if (fused) {
    unsigned short* Qp   = wsp;
    unsigned short* Kp   = wsp + PROJ;
    unsigned short* Vt   = wsp + 2 * PROJ;
    unsigned short* inq  = wsp + 3 * PROJ;  // later aliased as ctx
    unsigned short* ctx  = inq;
    unsigned short* ink  = wsp + 4 * PROJ;
    unsigned short* inv  = wsp + 5 * PROJ;
    unsigned short* wq16 = wsp + 6 * PROJ;
    unsigned short* wk16 = wq16 + WSZ;
    unsigned short* wv16 = wk16 + WSZ;
    unsigned short* ww16 = wv16 + WSZ;

    cvt_first_kernel<<<dim3(1024, 5), 256, 0, stream>>>(
        WQw, WKw, WVw, Ww, wq16, wk16, wv16, ww16, (int)(WSZ / 8),
        in_q, inq, (int)(PROJ / 8));
    gemm_kernel<0><<<2560, 256, 0, stream>>>(inq, wq16, WQb, Qp, 8192, 1024, 1024,
                                             qscale, 3, 512, in_k, ink, (int)(PROJ / 8));
    gemm_kernel<0><<<2560, 256, 0, stream>>>(ink, wk16, WKb, Kp, 8192, 1024, 1024,
                                             1.0f, 3, 512, in_v, inv, (int)(PROJ / 8));
    gemm_kernel<2><<<512, 256, 0, stream>>>(wv16, inv, WVb, Vt, 1024, 8192, 1024,
                                            1.0f, 6, 512, nullptr, nullptr, 0);
    attn9_kernel<<<1024, 256, 0, stream>>>(Qp, Kp, Vt, ctx);
    gemm_kernel<1><<<512, 256, 0, stream>>>(ctx, ww16, Wb, out, 8192, 1024, 1024,
                                            1.0f, 3, 512, nullptr, nullptr, 0);
  } else {
    unsigned short* Qp   = wsp;
    unsigned short* Kp   = wsp + PROJ;
    unsigned short* Vt   = wsp + 2 * PROJ;
    unsigned short* in16 = wsp + 3 * PROJ;
    unsigned short* ctx  = in16;
    unsigned short* wq16 = wsp + 4 * PROJ;
    unsigned short* wk16 = wq16 + WSZ;
    unsigned short* wv16 = wk16 + WSZ;
    unsigned short* ww16 = wv16 + WSZ;

    cvt_first_kernel<<<dim3(1024, 5), 256, 0, stream>>>(
        WQw, WKw, WVw, Ww, wq16, wk16, wv16, ww16, (int)(WSZ / 8),
        in_q, in16, (int)(PROJ / 8));
    gemm_kernel<0><<<512, 256, 0, stream>>>(in16, wq16, WQb, Qp, 8192, 1024, 1024,
                                            qscale, 3, 512, nullptr, nullptr, 0);
    cvt1_kernel<<<2048, 256, 0, stream>>>(in_k, in16, (int)(PROJ / 8));
    gemm_kernel<0><<<512, 256, 0, stream>>>(in16, wk16, WKb, Kp, 8192, 1024, 1024,
                                            1.0f, 3, 512, nullptr, nullptr, 0);
    cvt1_kernel<<<2048, 256, 0, stream>>>(in_v, in16, (int)(PROJ / 8));
    gemm_kernel<2><<<512, 256, 0, stream>>>(wv16, in16, WVb, Vt, 1024, 8192, 1024,
                                            1.0f, 6, 512, nullptr, nullptr, 0);
    attn9_kernel<<<1024, 256, 0, stream>>>(Qp, Kp, Vt, ctx);
    gemm_kernel<1><<<512, 256, 0, stream>>>(ctx, ww16, Wb, out, 8192, 1024, 1024,
                                            1.0f, 3, 512, nullptr, nullptr, 0);
  }
}